// Round 5
// baseline (294.294 us; speedup 1.0000x reference)
//
#include <hip/hip_runtime.h>
#include <math.h>
#include <stdint.h>

#define HH 256
#define LPB 5000

typedef _Float16 h2v  __attribute__((ext_vector_type(2)));
typedef _Float16 f16x8 __attribute__((ext_vector_type(8)));
typedef float    f32x4 __attribute__((ext_vector_type(4)));

__device__ __forceinline__ h2v u2h(unsigned int u) { return __builtin_bit_cast(h2v, u); }
__device__ __forceinline__ unsigned int h2u(h2v h) { return __builtin_bit_cast(unsigned int, h); }

__device__ __forceinline__ float fdot2(h2v a, unsigned int w, float c) {
#if __has_builtin(__builtin_amdgcn_fdot2)
    return __builtin_amdgcn_fdot2(a, u2h(w), c, false);
#else
    h2v b = u2h(w);
    return c + (float)a[0] * (float)b[0] + (float)a[1] * (float)b[1];
#endif
}

__device__ __forceinline__ h2v relu2(h2v a) {
    h2v z = (h2v)(_Float16)0.f;
#if __has_builtin(__builtin_elementwise_max)
    return __builtin_elementwise_max(a, z);
#else
    h2v r; r[0] = a[0] > z[0] ? a[0] : z[0]; r[1] = a[1] > z[1] ? a[1] : z[1]; return r;
#endif
}
__device__ __forceinline__ h2v hmax2v(h2v a, h2v b) {
#if __has_builtin(__builtin_elementwise_max)
    return __builtin_elementwise_max(a, b);
#else
    h2v r; r[0] = a[0] > b[0] ? a[0] : b[0]; r[1] = a[1] > b[1] ? a[1] : b[1]; return r;
#endif
}

// ---------------------------------------------------------------------------
// prep_small: f16 weight conversions + folded BN packs + fc2 weight pack.
// Block 249: spatial bucket-sort of lines -> perm (batch, 16x16-px midpoint
// tile; 512 buckets). Per-line results are order-independent, so processing
// in perm order with out[id] writes is bit-identical.
// ---------------------------------------------------------------------------
__global__ __launch_bounds__(256) void prep_small(
    const float* __restrict__ w_fc1, const float* __restrict__ c1w,
    const float* __restrict__ c2w,  const float* __restrict__ c3w,
    const float* __restrict__ wfc2, const float* __restrict__ bn1,
    const float* __restrict__ bn2,  const float* __restrict__ bn3,
    const float* __restrict__ lines,
    _Float16* __restrict__ wf16, _Float16* __restrict__ w1r,
    _Float16* __restrict__ w2r, _Float16* __restrict__ w3r,
    unsigned int* __restrict__ wfc2p, unsigned int* __restrict__ bn_pk,
    int* __restrict__ perm)
{
    if (blockIdx.x == 249) {            // ---- line bucket-sort ----
        __shared__ int cnt[512];
        __shared__ int base[512];
        const int t = threadIdx.x;
        for (int j = t; j < 512; j += 256) cnt[j] = 0;
        __syncthreads();
        for (int i = t; i < 10000; i += 256) {
            float4 ln = *(const float4*)(lines + i * 4);
            float mx = 0.5f * (ln.x + ln.z), my = 0.5f * (ln.y + ln.w);
            int bx = min(max((int)mx, 0), 255) >> 4;
            int by = min(max((int)my, 0), 255) >> 4;
            int bk = ((i >= LPB) ? 256 : 0) + by * 16 + bx;
            atomicAdd(&cnt[bk], 1);
        }
        __syncthreads();
        if (t == 0) {
            int s = 0;
            for (int j = 0; j < 512; j++) { base[j] = s; s += cnt[j]; }
        }
        __syncthreads();
        for (int i = t; i < 10000; i += 256) {
            float4 ln = *(const float4*)(lines + i * 4);
            float mx = 0.5f * (ln.x + ln.z), my = 0.5f * (ln.y + ln.w);
            int bx = min(max((int)mx, 0), 255) >> 4;
            int by = min(max((int)my, 0), 255) >> 4;
            int bk = ((i >= LPB) ? 256 : 0) + by * 16 + bx;
            int rank = atomicAdd(&base[bk], 1);
            perm[rank] = i;
        }
        return;
    }
    int i = blockIdx.x * 256 + threadIdx.x;
    if (i < 32768) { wf16[i] = (_Float16)w_fc1[i]; return; }
    i -= 32768;
    if (i < 8192) {                       // w1r[o][c] (same layout as c1_w)
        w1r[i] = (_Float16)c1w[i]; return;
    }
    i -= 8192;
    if (i < 12288) {                      // w2r[tap][o][i] from c2_w[o][i][tap]
        int ii = i & 63, o = (i >> 6) & 63, tap = i >> 12;
        w2r[i] = (_Float16)c2w[(o * 64 + ii) * 3 + tap]; return;
    }
    i -= 12288;
    if (i < 8192) {                       // w3r[o][i] (same layout as c3_w)
        w3r[i] = (_Float16)c3w[i]; return;
    }
    i -= 8192;
    if (i < 2048) {                       // wfc2p[(j*8+p)*64 + c2]
        int c2 = i & 63, p = (i >> 6) & 7, j = i >> 9;
        h2v v = { (_Float16)wfc2[j * 1024 + (2 * c2) * 8 + p],
                  (_Float16)wfc2[j * 1024 + (2 * c2 + 1) * 8 + p] };
        wfc2p[(j * 8 + p) * 64 + c2] = h2u(v); return;
    }
    i -= 2048;
    if (i < 128) {                        // bn packs: scale, shift = beta - mean*scale
        const float* bn; int C, base_, hcount;
        if (i < 64)      { bn = bn1; C = 128; base_ = 0;   hcount = 64; }
        else if (i < 96) { bn = bn2; C = 64;  base_ = 128; hcount = 32; i -= 64; }
        else             { bn = bn3; C = 64;  base_ = 192; hcount = 32; i -= 96; }
        int c0 = 2 * i, c1 = 2 * i + 1;
        float s0 = bn[c0] * rsqrtf(bn[3 * C + c0] + 1e-5f);
        float s1 = bn[c1] * rsqrtf(bn[3 * C + c1] + 1e-5f);
        float h0 = bn[C + c0] - bn[2 * C + c0] * s0;
        float h1 = bn[C + c1] - bn[2 * C + c1] * s1;
        h2v sv = { (_Float16)s0, (_Float16)s1 };
        h2v hv = { (_Float16)h0, (_Float16)h1 };
        bn_pk[base_ + i] = h2u(sv);
        bn_pk[base_ + hcount + i] = h2u(hv);
    }
}

// ---------------------------------------------------------------------------
// fc1_fused: round-1 verified version (best measured total).
// ---------------------------------------------------------------------------
__global__ __launch_bounds__(256, 4) void fc1_fused(
    const float* __restrict__ feat,   // [B,256,65536]
    const _Float16* __restrict__ W,   // [128][256] f16
    const float* __restrict__ bias,
    unsigned int* __restrict__ X)     // [131072][64] h2 units
{
    __shared__ float Tf[32 * 132];    // f32 feature tile [c][pix], pad 132
    __shared__ _Float16 Wl[128 * 40]; // f16 W tile [o][k], pad 40
    const int t = threadIdx.x;
    const int lane = t & 63, wave = t >> 6;
    const int wm = wave & 1, wn = wave >> 1;
    const int pix0g = blockIdx.x << 7;              // global pixel base
    const int b = blockIdx.x >> 9;
    const int pix0l = pix0g & 65535;                // within batch
    const float* fbase = feat + (size_t)b * (256u * 65536u) + pix0l;

    f32x4 acc[4][4];
#pragma unroll
    for (int a = 0; a < 4; a++)
#pragma unroll
        for (int c = 0; c < 4; c++) acc[a][c] = (f32x4)0.f;

    for (int ks = 0; ks < 8; ks++) {
        const int k0 = ks * 32;
        __syncthreads();
#pragma unroll
        for (int r = 0; r < 4; r++) {               // 32 c x 128 pix f32
            int idx = t + r * 256;
            int c = idx >> 5, p4 = idx & 31;
            float4 v = *(const float4*)(fbase + (size_t)(k0 + c) * 65536 + p4 * 4);
            *(float4*)&Tf[c * 132 + p4 * 4] = v;
        }
#pragma unroll
        for (int r = 0; r < 2; r++) {               // 128 o x 32 k f16
            int idx = t + r * 256;
            int row = idx >> 2, ko = (idx & 3) * 8;
            *(uint4*)&Wl[row * 40 + ko] = *(const uint4*)(W + row * 256 + k0 + ko);
        }
        __syncthreads();
        f16x8 af[4], bf[4];
#pragma unroll
        for (int mt = 0; mt < 4; mt++)
            af[mt] = *(const f16x8*)&Wl[(wm * 64 + mt * 16 + (lane & 15)) * 40 + (lane >> 4) * 8];
#pragma unroll
        for (int nt = 0; nt < 4; nt++) {
            int q = wn * 64 + nt * 16 + (lane & 15);
            int cb = (lane >> 4) * 8;
            f16x8 v;
#pragma unroll
            for (int j = 0; j < 8; j++) v[j] = (_Float16)Tf[(cb + j) * 132 + q];
            bf[nt] = v;
        }
#pragma unroll
        for (int mt = 0; mt < 4; mt++)
#pragma unroll
            for (int nt = 0; nt < 4; nt++)
                acc[mt][nt] = __builtin_amdgcn_mfma_f32_16x16x32_f16(af[mt], bf[nt], acc[mt][nt], 0, 0, 0);
    }
#pragma unroll
    for (int mt = 0; mt < 4; mt++) {
        int o = wm * 64 + mt * 16 + (lane >> 4) * 4;
        float4 b4 = *(const float4*)(bias + o);
#pragma unroll
        for (int nt = 0; nt < 4; nt++) {
            int pix = pix0g + wn * 64 + nt * 16 + (lane & 15);
            f32x4 a = acc[mt][nt];
            h2v lo = { (_Float16)(a[0] + b4.x), (_Float16)(a[1] + b4.y) };
            h2v hi = { (_Float16)(a[2] + b4.z), (_Float16)(a[3] + b4.w) };
            uint2 v = { h2u(lo), h2u(hi) };
            *(uint2*)(X + (size_t)pix * 64 + (o >> 1)) = v;
        }
    }
}

// ---------------------------------------------------------------------------
// line_v6: line_v5 + perm-ordered line processing (spatially bucketed) +
// bijective XCD chunking (1250 = 8*156+2, m204 formula) so consecutive
// (spatially-adjacent) blocks share an XCD L2. Results written to out[id].
// ---------------------------------------------------------------------------
__global__ __launch_bounds__(256, 4) void line_v6(
    const unsigned int* __restrict__ X,      // [131072][64] h2 units
    const float* __restrict__ lines,
    const int* __restrict__ perm,
    const _Float16* __restrict__ w1r, const float* __restrict__ c1b,
    const _Float16* __restrict__ w2r, const float* __restrict__ c2b,
    const _Float16* __restrict__ w3r, const float* __restrict__ c3b,
    const unsigned int* __restrict__ wfc2p, const float* __restrict__ bfc2,
    const unsigned int* __restrict__ bn_pk,
    float* __restrict__ out)
{
    __shared__ int geoB[256];
    __shared__ unsigned int geoWA[256], geoWB[256];
    __shared__ unsigned int xp[64 * 68];     // raw pooled feats [col][o2], 17408 B
    __shared__ unsigned int abuf[64 * 68];   // a1 [col][c2]@68 -> a2 [colp80][i2]@36 -> a3 [col][i2]@36
    __shared__ float red[128];

    const int t = threadIdx.x;
    // bijective XCD swizzle: orig%8 -> contiguous chunk per XCD (1250=8*156+2)
    const int orig = blockIdx.x;
    const int xcd = orig & 7, loc = orig >> 3;
    const int bid = (xcd < 2 ? xcd * 157 : 2 * 157 + (xcd - 2) * 156) + loc;
    const int n0 = bid * 8;
    const int lane = t & 63;
    const int w = t >> 6;
    const int l15 = lane & 15;
    const int kg = lane >> 4;            // k-group 0..3
    const int ko8 = kg * 8;              // k offset in halves

    // ---- geometry: one thread per sample point ----
    {
        int l = t >> 5, k = t & 31;
        int id = perm[n0 + l];
        float4 ln = *(const float4*)(lines + id * 4);
        float lam = (float)k / 31.0f;
        float px = ln.x * lam + ln.z * (1.f - lam) - 0.5f;
        float py = ln.y * lam + ln.w * (1.f - lam) - 0.5f;
        float px0 = fminf(fmaxf(floorf(px), 0.f), 255.f);
        float py0 = fminf(fmaxf(floorf(py), 0.f), 255.f);
        float dx = px - px0, dy = py - py0;
        float ex = 1.f - dx, ey = 1.f - dy;
        h2v wA = { (_Float16)(ex * ey), (_Float16)(dx * ey) };
        h2v wB = { (_Float16)(ex * dy), (_Float16)(dx * dy) };
        int b = (id >= LPB) ? 1 : 0;
        int pixflat = (b << 16) + ((int)px0 << 8) + (int)py0;
        geoB[t] = pixflat << 6;                  // h2-unit index
        geoWA[t] = h2u(wA); geoWB[t] = h2u(wB);
    }
    __syncthreads();

    // ---- gather + maxpool4, loads hoisted 16-deep; dual write ----
    {
        const int c8 = t & 15;          // channel-oct 0..15 (8 ch each)
        const int sub = t >> 4;         // 0..15
        const int line = sub >> 1;
        const int gbase = (sub & 1) * 4;
        const uint4* xq = (const uint4*)X;
        uint4 s1 = *(const uint4*)(bn_pk + c8 * 4);
        uint4 h1 = *(const uint4*)(bn_pk + 64 + c8 * 4);
#pragma unroll
        for (int lg = 0; lg < 4; lg++) {
            int g = gbase + lg;
            int ptb = line * 32 + g * 4;
            uint4 q[4][4];
            unsigned int wAv[4], wBv[4];
#pragma unroll
            for (int s = 0; s < 4; s++) {           // issue all 16 loads first
                int pt = ptb + s;
                int base4 = (geoB[pt] >> 2) + c8;
                wAv[s] = geoWA[pt]; wBv[s] = geoWB[pt];
                q[s][0] = xq[base4];
                q[s][1] = xq[base4 + 4096];
                q[s][2] = xq[base4 + 16];
                q[s][3] = xq[base4 + 4112];
            }
            h2v m0, m1, m2, m3;
#pragma unroll
            for (int s = 0; s < 4; s++) {           // then blend + max
                h2v wA = u2h(wAv[s]), wB = u2h(wBv[s]);
                h2v w00 = { wA[0], wA[0] }, w10 = { wA[1], wA[1] };
                h2v w01 = { wB[0], wB[0] }, w11 = { wB[1], wB[1] };
                h2v v0 = u2h(q[s][0].x) * w00 + u2h(q[s][1].x) * w10 + u2h(q[s][2].x) * w01 + u2h(q[s][3].x) * w11;
                h2v v1 = u2h(q[s][0].y) * w00 + u2h(q[s][1].y) * w10 + u2h(q[s][2].y) * w01 + u2h(q[s][3].y) * w11;
                h2v v2 = u2h(q[s][0].z) * w00 + u2h(q[s][1].z) * w10 + u2h(q[s][2].z) * w01 + u2h(q[s][3].z) * w11;
                h2v v3 = u2h(q[s][0].w) * w00 + u2h(q[s][1].w) * w10 + u2h(q[s][2].w) * w01 + u2h(q[s][3].w) * w11;
                if (s == 0) { m0 = v0; m1 = v1; m2 = v2; m3 = v3; }
                else { m0 = hmax2v(m0, v0); m1 = hmax2v(m1, v1);
                       m2 = hmax2v(m2, v2); m3 = hmax2v(m3, v3); }
            }
            int colw = line * 8 + g;
            uint4 raw = { h2u(m0), h2u(m1), h2u(m2), h2u(m3) };
            *(uint4*)&xp[colw * 68 + c8 * 4] = raw;
            h2v r0 = relu2(m0 * u2h(s1.x) + u2h(h1.x));
            h2v r1 = relu2(m1 * u2h(s1.y) + u2h(h1.y));
            h2v r2 = relu2(m2 * u2h(s1.z) + u2h(h1.z));
            h2v r3 = relu2(m3 * u2h(s1.w) + u2h(h1.w));
            uint4 act = { h2u(r0), h2u(r1), h2u(r2), h2u(r3) };
            *(uint4*)&abuf[colw * 68 + c8 * 4] = act;
        }
    }
    __syncthreads();

    // ---- c1: out[64o x 64col], K=128 MFMA. wave w -> o-tile w ----
    f32x4 acc1[4];
#pragma unroll
    for (int nt = 0; nt < 4; nt++) acc1[nt] = (f32x4)0.f;
    {
        const int o = w * 16 + l15;
        f16x8 af[4];
#pragma unroll
        for (int kt = 0; kt < 4; kt++)
            af[kt] = *(const f16x8*)(w1r + o * 128 + kt * 32 + ko8);
        __builtin_amdgcn_s_setprio(1);
#pragma unroll
        for (int nt = 0; nt < 4; nt++) {
            const int colb = nt * 16 + l15;
#pragma unroll
            for (int kt = 0; kt < 4; kt++) {
                f16x8 bf = *(const f16x8*)&abuf[colb * 68 + kt * 16 + kg * 4];
                acc1[nt] = __builtin_amdgcn_mfma_f32_16x16x32_f16(af[kt], bf, acc1[nt], 0, 0, 0);
            }
        }
        __builtin_amdgcn_s_setprio(0);
    }
    __syncthreads();

    // ---- a2 = relu(bn2(c1+b)) into padded [colp=line*10+1+p][i2]@36, zero pads ----
    {
        float4 b1 = *(const float4*)(c1b + w * 16 + kg * 4);
        const int o2 = w * 8 + kg * 2;
        h2v sA = u2h(bn_pk[128 + o2]), sB = u2h(bn_pk[128 + o2 + 1]);
        h2v hA = u2h(bn_pk[160 + o2]), hB = u2h(bn_pk[160 + o2 + 1]);
#pragma unroll
        for (int nt = 0; nt < 4; nt++) {
            const int col = nt * 16 + l15;
            const int colp = (col >> 3) * 10 + 1 + (col & 7);
            h2v v0 = { (_Float16)(acc1[nt][0] + b1.x), (_Float16)(acc1[nt][1] + b1.y) };
            h2v v1 = { (_Float16)(acc1[nt][2] + b1.z), (_Float16)(acc1[nt][3] + b1.w) };
            v0 = relu2(v0 * sA + hA);
            v1 = relu2(v1 * sB + hB);
            uint2 u = { h2u(v0), h2u(v1) };
            *(uint2*)&abuf[colp * 36 + o2] = u;
        }
#pragma unroll
        for (int e = 0; e < 2; e++) {   // zero the 16 pad columns x 32 i2
            int idx = t * 2 + e;
            int pc = idx >> 5, i2 = idx & 31;
            int pl = pc >> 1, side = pc & 1;
            abuf[(pl * 10 + side * 9) * 36 + i2] = 0;
        }
    }
    __syncthreads();

    // ---- c2: 3-tap conv as 3 shifted GEMMs, K=64. wave w -> o-tile w ----
    f32x4 acc2[4];
#pragma unroll
    for (int nt = 0; nt < 4; nt++) acc2[nt] = (f32x4)0.f;
    {
        const int o = w * 16 + l15;
        const int colp0 = (l15 >> 3) * 10 + 1 + (l15 & 7);
        __builtin_amdgcn_s_setprio(1);
#pragma unroll
        for (int tap = 0; tap < 3; tap++) {
            f16x8 wa0 = *(const f16x8*)(w2r + (tap * 64 + o) * 64 + ko8);
            f16x8 wa1 = *(const f16x8*)(w2r + (tap * 64 + o) * 64 + 32 + ko8);
#pragma unroll
            for (int nt = 0; nt < 4; nt++) {
                const int cp = colp0 + nt * 20 + tap - 1;
                f16x8 b0 = *(const f16x8*)&abuf[cp * 36 + kg * 4];
                f16x8 b1 = *(const f16x8*)&abuf[cp * 36 + 16 + kg * 4];
                acc2[nt] = __builtin_amdgcn_mfma_f32_16x16x32_f16(wa0, b0, acc2[nt], 0, 0, 0);
                acc2[nt] = __builtin_amdgcn_mfma_f32_16x16x32_f16(wa1, b1, acc2[nt], 0, 0, 0);
            }
        }
        __builtin_amdgcn_s_setprio(0);
    }
    __syncthreads();

    // ---- a3 = relu(bn3(c2+b)) into [col][i2]@36 ----
    {
        float4 b2 = *(const float4*)(c2b + w * 16 + kg * 4);
        const int o2 = w * 8 + kg * 2;
        h2v sA = u2h(bn_pk[192 + o2]), sB = u2h(bn_pk[192 + o2 + 1]);
        h2v hA = u2h(bn_pk[224 + o2]), hB = u2h(bn_pk[224 + o2 + 1]);
#pragma unroll
        for (int nt = 0; nt < 4; nt++) {
            const int col = nt * 16 + l15;
            h2v v0 = { (_Float16)(acc2[nt][0] + b2.x), (_Float16)(acc2[nt][1] + b2.y) };
            h2v v1 = { (_Float16)(acc2[nt][2] + b2.z), (_Float16)(acc2[nt][3] + b2.w) };
            v0 = relu2(v0 * sA + hA);
            v1 = relu2(v1 * sB + hB);
            uint2 u = { h2u(v0), h2u(v1) };
            *(uint2*)&abuf[col * 36 + o2] = u;
        }
    }
    __syncthreads();

    // ---- c3: out[128o x 64col], K=64 + residual + relu -> y in-place into xp ----
    {
#pragma unroll
        for (int mi = 0; mi < 2; mi++) {
            const int om = (2 * w + mi) * 16 + l15;
            f16x8 af0 = *(const f16x8*)(w3r + om * 64 + ko8);
            f16x8 af1 = *(const f16x8*)(w3r + om * 64 + 32 + ko8);
            f32x4 acc3[4];
#pragma unroll
            for (int nt = 0; nt < 4; nt++) acc3[nt] = (f32x4)0.f;
            __builtin_amdgcn_s_setprio(1);
#pragma unroll
            for (int nt = 0; nt < 4; nt++) {
                const int col = nt * 16 + l15;
                f16x8 b0 = *(const f16x8*)&abuf[col * 36 + kg * 4];
                f16x8 b1 = *(const f16x8*)&abuf[col * 36 + 16 + kg * 4];
                acc3[nt] = __builtin_amdgcn_mfma_f32_16x16x32_f16(af0, b0, acc3[nt], 0, 0, 0);
                acc3[nt] = __builtin_amdgcn_mfma_f32_16x16x32_f16(af1, b1, acc3[nt], 0, 0, 0);
            }
            __builtin_amdgcn_s_setprio(0);
            float4 b3 = *(const float4*)(c3b + (2 * w + mi) * 16 + kg * 4);
            const int o2 = (2 * w + mi) * 8 + kg * 2;
#pragma unroll
            for (int nt = 0; nt < 4; nt++) {
                const int col = nt * 16 + l15;
                uint2 xv = *(const uint2*)&xp[col * 68 + o2];
                h2v y0 = { (_Float16)(acc3[nt][0] + b3.x), (_Float16)(acc3[nt][1] + b3.y) };
                h2v y1 = { (_Float16)(acc3[nt][2] + b3.z), (_Float16)(acc3[nt][3] + b3.w) };
                y0 = relu2(u2h(xv.x) + y0);
                y1 = relu2(u2h(xv.y) + y1);
                uint2 u = { h2u(y0), h2u(y1) };
                *(uint2*)&xp[col * 68 + o2] = u;
            }
        }
    }
    __syncthreads();

    // ---- fc2 partial (y from xp) + reduce ----
    {
        const int og = w;
        const int col = t & 63;
        const int obH = __builtin_amdgcn_readfirstlane(og * 16);  // o2 base
        const int p = col & 7, l = col >> 3;
        h2v yv[16];
#pragma unroll
        for (int j = 0; j < 16; j++) yv[j] = u2h(xp[col * 68 + obH + j]);
        float aj[4] = { 0.f, 0.f, 0.f, 0.f };
#pragma unroll
        for (int j = 0; j < 4; j++) {
            unsigned int wv2[16];
#pragma unroll
            for (int q = 0; q < 4; q++)
                *(uint4*)&wv2[q * 4] = *(const uint4*)(wfc2p + (j * 8 + p) * 64 + obH + q * 4);
#pragma unroll
            for (int j16 = 0; j16 < 16; j16++) aj[j] = fdot2(yv[j16], wv2[j16], aj[j]);
        }
#pragma unroll
        for (int off = 4; off > 0; off >>= 1) {
#pragma unroll
            for (int j = 0; j < 4; j++) aj[j] += __shfl_down(aj[j], off, 8);
        }
        if ((t & 7) == 0) {
#pragma unroll
            for (int j = 0; j < 4; j++) red[og * 32 + l * 4 + j] = aj[j];
        }
    }
    __syncthreads();

    // ---- final reduce + softmax; write to ORIGINAL line index ----
    if (t < 8) {
        int id = perm[n0 + t];
        float lg[4];
#pragma unroll
        for (int j = 0; j < 4; j++)
            lg[j] = bfc2[j] + red[t * 4 + j] + red[32 + t * 4 + j]
                  + red[64 + t * 4 + j] + red[96 + t * 4 + j];
        float mx = fmaxf(fmaxf(lg[0], lg[1]), fmaxf(lg[2], lg[3]));
        float e0 = expf(lg[0] - mx), e1 = expf(lg[1] - mx);
        float e2 = expf(lg[2] - mx), e3 = expf(lg[3] - mx);
        float s = 1.f / (e0 + e1 + e2 + e3);
        float4 r = { e0 * s, e1 * s, e2 * s, e3 * s };
        *(float4*)(out + (size_t)id * 4) = r;
    }
}

extern "C" void kernel_launch(void* const* d_in, const int* in_sizes, int n_in,
                              void* d_out, int out_size, void* d_ws, size_t ws_size,
                              hipStream_t stream) {
    const float* feature = (const float*)d_in[0];
    const float* lines   = (const float*)d_in[1];
    const float* w_fc1   = (const float*)d_in[2];
    const float* b_fc1   = (const float*)d_in[3];
    const float* bn1     = (const float*)d_in[4];
    const float* c1_w    = (const float*)d_in[5];
    const float* c1_b    = (const float*)d_in[6];
    const float* bn2     = (const float*)d_in[7];
    const float* c2_w    = (const float*)d_in[8];
    const float* c2_b    = (const float*)d_in[9];
    const float* bn3     = (const float*)d_in[10];
    const float* c3_w    = (const float*)d_in[11];
    const float* c3_b    = (const float*)d_in[12];
    const float* w_fc2   = (const float*)d_in[13];
    const float* b_fc2   = (const float*)d_in[14];
    float* out = (float*)d_out;

    char* ws = (char*)d_ws;
    unsigned int* X     = (unsigned int*)ws;                 // 33,554,432 B
    _Float16*     wf16  = (_Float16*)(ws + 33554432);        // 65,536 B
    _Float16*     w1r   = (_Float16*)(ws + 33619968);        // 16,384 B
    _Float16*     w2r   = (_Float16*)(ws + 33636352);        // 24,576 B
    _Float16*     w3r   = (_Float16*)(ws + 33660928);        // 16,384 B
    unsigned int* wfc2p = (unsigned int*)(ws + 33677312);    // 8,192 B
    unsigned int* bn_pk = (unsigned int*)(ws + 33685504);    // 1,024 B
    int*          perm  = (int*)(ws + 33686528);             // 40,000 B

    prep_small<<<250, 256, 0, stream>>>(w_fc1, c1_w, c2_w, c3_w, w_fc2, bn1, bn2, bn3,
                                        lines, wf16, w1r, w2r, w3r, wfc2p, bn_pk, perm);
    fc1_fused<<<1024, 256, 0, stream>>>(feature, wf16, b_fc1, X);
    line_v6<<<1250, 256, 0, stream>>>(X, lines, perm, w1r, c1_b, w2r, c2_b,
                                      w3r, c3_b, wfc2p, b_fc2, bn_pk, out);
}

// Round 6
// 271.562 us; speedup vs baseline: 1.0837x; 1.0837x over previous
//
#include <hip/hip_runtime.h>
#include <math.h>
#include <stdint.h>

#define HH 256
#define LPB 5000

typedef _Float16 h2v  __attribute__((ext_vector_type(2)));
typedef _Float16 f16x8 __attribute__((ext_vector_type(8)));
typedef float    f32x4 __attribute__((ext_vector_type(4)));

__device__ __forceinline__ h2v u2h(unsigned int u) { return __builtin_bit_cast(h2v, u); }
__device__ __forceinline__ unsigned int h2u(h2v h) { return __builtin_bit_cast(unsigned int, h); }

__device__ __forceinline__ float fdot2(h2v a, unsigned int w, float c) {
#if __has_builtin(__builtin_amdgcn_fdot2)
    return __builtin_amdgcn_fdot2(a, u2h(w), c, false);
#else
    h2v b = u2h(w);
    return c + (float)a[0] * (float)b[0] + (float)a[1] * (float)b[1];
#endif
}

__device__ __forceinline__ h2v relu2(h2v a) {
    h2v z = (h2v)(_Float16)0.f;
#if __has_builtin(__builtin_elementwise_max)
    return __builtin_elementwise_max(a, z);
#else
    h2v r; r[0] = a[0] > z[0] ? a[0] : z[0]; r[1] = a[1] > z[1] ? a[1] : z[1]; return r;
#endif
}
__device__ __forceinline__ h2v hmax2v(h2v a, h2v b) {
#if __has_builtin(__builtin_elementwise_max)
    return __builtin_elementwise_max(a, b);
#else
    h2v r; r[0] = a[0] > b[0] ? a[0] : b[0]; r[1] = a[1] > b[1] ? a[1] : b[1]; return r;
#endif
}

// ---------------------------------------------------------------------------
// prep_small: f16 weight conversions (row-major for MFMA A-operands) + folded
// BN packs + fc2 weight pack.  (round-1 version, perm/sort removed)
// ---------------------------------------------------------------------------
__global__ __launch_bounds__(256) void prep_small(
    const float* __restrict__ w_fc1, const float* __restrict__ c1w,
    const float* __restrict__ c2w,  const float* __restrict__ c3w,
    const float* __restrict__ wfc2, const float* __restrict__ bn1,
    const float* __restrict__ bn2,  const float* __restrict__ bn3,
    _Float16* __restrict__ wf16, _Float16* __restrict__ w1r,
    _Float16* __restrict__ w2r, _Float16* __restrict__ w3r,
    unsigned int* __restrict__ wfc2p, unsigned int* __restrict__ bn_pk)
{
    int i = blockIdx.x * 256 + threadIdx.x;
    if (i < 32768) { wf16[i] = (_Float16)w_fc1[i]; return; }
    i -= 32768;
    if (i < 8192) {                       // w1r[o][c] (same layout as c1_w)
        w1r[i] = (_Float16)c1w[i]; return;
    }
    i -= 8192;
    if (i < 12288) {                      // w2r[tap][o][i] from c2_w[o][i][tap]
        int ii = i & 63, o = (i >> 6) & 63, tap = i >> 12;
        w2r[i] = (_Float16)c2w[(o * 64 + ii) * 3 + tap]; return;
    }
    i -= 12288;
    if (i < 8192) {                       // w3r[o][i] (same layout as c3_w)
        w3r[i] = (_Float16)c3w[i]; return;
    }
    i -= 8192;
    if (i < 2048) {                       // wfc2p[(j*8+p)*64 + c2]
        int c2 = i & 63, p = (i >> 6) & 7, j = i >> 9;
        h2v v = { (_Float16)wfc2[j * 1024 + (2 * c2) * 8 + p],
                  (_Float16)wfc2[j * 1024 + (2 * c2 + 1) * 8 + p] };
        wfc2p[(j * 8 + p) * 64 + c2] = h2u(v); return;
    }
    i -= 2048;
    if (i < 128) {                        // bn packs: scale, shift = beta - mean*scale
        const float* bn; int C, base, hcount;
        if (i < 64)      { bn = bn1; C = 128; base = 0;   hcount = 64; }
        else if (i < 96) { bn = bn2; C = 64;  base = 128; hcount = 32; i -= 64; }
        else             { bn = bn3; C = 64;  base = 192; hcount = 32; i -= 96; }
        int c0 = 2 * i, c1 = 2 * i + 1;
        float s0 = bn[c0] * rsqrtf(bn[3 * C + c0] + 1e-5f);
        float s1 = bn[c1] * rsqrtf(bn[3 * C + c1] + 1e-5f);
        float h0 = bn[C + c0] - bn[2 * C + c0] * s0;
        float h1 = bn[C + c1] - bn[2 * C + c1] * s1;
        h2v sv = { (_Float16)s0, (_Float16)s1 };
        h2v hv = { (_Float16)h0, (_Float16)h1 };
        bn_pk[base + i] = h2u(sv);
        bn_pk[base + hcount + i] = h2u(hv);
    }
}

// ---------------------------------------------------------------------------
// fc1_fused v5: same 128o x 128px tile and LDS layout as the verified round-1
// version, but 512 threads / 8 waves per block (each wave 64o x 32px,
// acc[4][2]).  Total resident waves/CU rises 16 -> 24-32, hiding the per-step
// HBM stage latency via TLP (grid 1024 blocks x 8 waves = 8192 waves).
// launch_bounds(512,6): cap ~85 VGPR -> >=3 blocks/CU; core live regs ~45.
// ---------------------------------------------------------------------------
__global__ __launch_bounds__(512, 6) void fc1_fused(
    const float* __restrict__ feat,   // [B,256,65536]
    const _Float16* __restrict__ W,   // [128][256] f16
    const float* __restrict__ bias,
    unsigned int* __restrict__ X)     // [131072][64] h2 units
{
    __shared__ float Tf[32 * 132];    // f32 feature tile [c][pix], pad 132
    __shared__ _Float16 Wl[128 * 40]; // f16 W tile [o][k], pad 40
    const int t = threadIdx.x;
    const int lane = t & 63, wave = t >> 6;       // wave 0..7
    const int wm = wave & 1, wn = wave >> 1;      // wm 0..1, wn 0..3
    const int l15 = lane & 15, kg = lane >> 4;
    const int pix0g = blockIdx.x << 7;            // global pixel base
    const int b = blockIdx.x >> 9;
    const int pix0l = pix0g & 65535;              // within batch
    const float* fbase = feat + (size_t)b * (256u * 65536u) + pix0l;

    f32x4 acc[4][2];
#pragma unroll
    for (int a = 0; a < 4; a++)
#pragma unroll
        for (int c = 0; c < 2; c++) acc[a][c] = (f32x4)0.f;

    for (int ks = 0; ks < 8; ks++) {
        const int k0 = ks * 32;
        __syncthreads();
#pragma unroll
        for (int r = 0; r < 2; r++) {             // 32 c x 128 pix f32
            int idx = t + r * 512;
            int c = idx >> 5, p4 = idx & 31;
            float4 v = *(const float4*)(fbase + (size_t)(k0 + c) * 65536 + p4 * 4);
            *(float4*)&Tf[c * 132 + p4 * 4] = v;
        }
        {                                         // 128 o x 32 k f16, one round
            int row = t >> 2, ko = (t & 3) * 8;
            *(uint4*)&Wl[row * 40 + ko] = *(const uint4*)(W + row * 256 + k0 + ko);
        }
        __syncthreads();
        // B fragments first (2 per wave), then per-mt A fragment + MFMA
        f16x8 bf[2];
#pragma unroll
        for (int nt = 0; nt < 2; nt++) {
            int q = wn * 32 + nt * 16 + l15;
            int cb = kg * 8;
            f16x8 v;
#pragma unroll
            for (int j = 0; j < 8; j++) v[j] = (_Float16)Tf[(cb + j) * 132 + q];
            bf[nt] = v;
        }
#pragma unroll
        for (int mt = 0; mt < 4; mt++) {
            f16x8 af = *(const f16x8*)&Wl[(wm * 64 + mt * 16 + l15) * 40 + kg * 8];
#pragma unroll
            for (int nt = 0; nt < 2; nt++)
                acc[mt][nt] = __builtin_amdgcn_mfma_f32_16x16x32_f16(af, bf[nt], acc[mt][nt], 0, 0, 0);
        }
    }
#pragma unroll
    for (int mt = 0; mt < 4; mt++) {
        int o = wm * 64 + mt * 16 + (lane >> 4) * 4;
        float4 b4 = *(const float4*)(bias + o);
#pragma unroll
        for (int nt = 0; nt < 2; nt++) {
            int pix = pix0g + wn * 32 + nt * 16 + (lane & 15);
            f32x4 a = acc[mt][nt];
            h2v lo = { (_Float16)(a[0] + b4.x), (_Float16)(a[1] + b4.y) };
            h2v hi = { (_Float16)(a[2] + b4.z), (_Float16)(a[3] + b4.w) };
            uint2 v = { h2u(lo), h2u(hi) };
            *(uint2*)(X + (size_t)pix * 64 + (o >> 1)) = v;
        }
    }
}

// ---------------------------------------------------------------------------
// line_v4: round-1 verified version (best measured total), unchanged.
// ---------------------------------------------------------------------------
__global__ __launch_bounds__(256, 4) void line_v4(
    const unsigned int* __restrict__ X,      // [131072][64] h2 units
    const float* __restrict__ lines,
    const _Float16* __restrict__ w1r, const float* __restrict__ c1b,
    const _Float16* __restrict__ w2r, const float* __restrict__ c2b,
    const _Float16* __restrict__ w3r, const float* __restrict__ c3b,
    const unsigned int* __restrict__ wfc2p, const float* __restrict__ bfc2,
    const unsigned int* __restrict__ bn_pk,
    float* __restrict__ out)
{
    __shared__ int geoB[256];
    __shared__ unsigned int geoWA[256], geoWB[256];
    __shared__ unsigned int xp[64 * 68];     // raw pooled feats [col][o2], 17408 B
    __shared__ unsigned int abuf[64 * 68];   // a1 [col][c2]@68 -> a2 [colp80][i2]@36 -> a3 [col][i2]@36
    __shared__ float red[128];

    const int t = threadIdx.x;
    const int n0 = blockIdx.x * 8;
    const int lane = t & 63;
    const int w = t >> 6;
    const int l15 = lane & 15;
    const int kg = lane >> 4;            // k-group 0..3
    const int ko8 = kg * 8;              // k offset in halves

    // ---- geometry: one thread per sample point ----
    {
        int l = t >> 5, k = t & 31;
        int n = n0 + l;
        float4 ln = *(const float4*)(lines + n * 4);
        float lam = (float)k / 31.0f;
        float px = ln.x * lam + ln.z * (1.f - lam) - 0.5f;
        float py = ln.y * lam + ln.w * (1.f - lam) - 0.5f;
        float px0 = fminf(fmaxf(floorf(px), 0.f), 255.f);
        float py0 = fminf(fmaxf(floorf(py), 0.f), 255.f);
        float dx = px - px0, dy = py - py0;
        float ex = 1.f - dx, ey = 1.f - dy;
        h2v wA = { (_Float16)(ex * ey), (_Float16)(dx * ey) };
        h2v wB = { (_Float16)(ex * dy), (_Float16)(dx * dy) };
        int b = (n >= LPB) ? 1 : 0;
        int pixflat = (b << 16) + ((int)px0 << 8) + (int)py0;
        geoB[t] = pixflat << 6;                  // h2-unit index
        geoWA[t] = h2u(wA); geoWB[t] = h2u(wB);
    }
    __syncthreads();

    // ---- gather + maxpool4, dual write: raw -> xp, relu(bn1(.)) -> abuf ----
    {
        const int c8 = t & 15;          // channel-oct 0..15 (8 ch each)
        const int sub = t >> 4;         // 0..15
        const int line = sub >> 1;
        const int gbase = (sub & 1) * 4;
        const uint4* xq = (const uint4*)X;
        uint4 s1 = *(const uint4*)(bn_pk + c8 * 4);
        uint4 h1 = *(const uint4*)(bn_pk + 64 + c8 * 4);
#pragma unroll
        for (int lg = 0; lg < 4; lg++) {
            int g = gbase + lg;
            int ptb = line * 32 + g * 4;
            h2v m0, m1, m2, m3;
#pragma unroll
            for (int s = 0; s < 4; s++) {
                int pt = ptb + s;
                int base4 = (geoB[pt] >> 2) + c8;
                h2v wA = u2h(geoWA[pt]), wB = u2h(geoWB[pt]);
                uint4 q00 = xq[base4];
                uint4 q10 = xq[base4 + 4096];
                uint4 q01 = xq[base4 + 16];
                uint4 q11 = xq[base4 + 4112];
                h2v w00 = { wA[0], wA[0] }, w10 = { wA[1], wA[1] };
                h2v w01 = { wB[0], wB[0] }, w11 = { wB[1], wB[1] };
                h2v v0 = u2h(q00.x) * w00 + u2h(q10.x) * w10 + u2h(q01.x) * w01 + u2h(q11.x) * w11;
                h2v v1 = u2h(q00.y) * w00 + u2h(q10.y) * w10 + u2h(q01.y) * w01 + u2h(q11.y) * w11;
                h2v v2 = u2h(q00.z) * w00 + u2h(q10.z) * w10 + u2h(q01.z) * w01 + u2h(q11.z) * w11;
                h2v v3 = u2h(q00.w) * w00 + u2h(q10.w) * w10 + u2h(q01.w) * w01 + u2h(q11.w) * w11;
                if (s == 0) { m0 = v0; m1 = v1; m2 = v2; m3 = v3; }
                else { m0 = hmax2v(m0, v0); m1 = hmax2v(m1, v1);
                       m2 = hmax2v(m2, v2); m3 = hmax2v(m3, v3); }
            }
            int colw = line * 8 + g;
            uint4 raw = { h2u(m0), h2u(m1), h2u(m2), h2u(m3) };
            *(uint4*)&xp[colw * 68 + c8 * 4] = raw;
            h2v r0 = relu2(m0 * u2h(s1.x) + u2h(h1.x));
            h2v r1 = relu2(m1 * u2h(s1.y) + u2h(h1.y));
            h2v r2 = relu2(m2 * u2h(s1.z) + u2h(h1.z));
            h2v r3 = relu2(m3 * u2h(s1.w) + u2h(h1.w));
            uint4 act = { h2u(r0), h2u(r1), h2u(r2), h2u(r3) };
            *(uint4*)&abuf[colw * 68 + c8 * 4] = act;
        }
    }
    __syncthreads();

    // ---- c1: out[64o x 64col], K=128 MFMA. wave w -> o-tile w ----
    f32x4 acc1[4];
#pragma unroll
    for (int nt = 0; nt < 4; nt++) acc1[nt] = (f32x4)0.f;
    {
        const int o = w * 16 + l15;
        f16x8 af[4];
#pragma unroll
        for (int kt = 0; kt < 4; kt++)
            af[kt] = *(const f16x8*)(w1r + o * 128 + kt * 32 + ko8);
#pragma unroll
        for (int nt = 0; nt < 4; nt++) {
            const int colb = nt * 16 + l15;
#pragma unroll
            for (int kt = 0; kt < 4; kt++) {
                f16x8 bf = *(const f16x8*)&abuf[colb * 68 + kt * 16 + kg * 4];
                acc1[nt] = __builtin_amdgcn_mfma_f32_16x16x32_f16(af[kt], bf, acc1[nt], 0, 0, 0);
            }
        }
    }
    __syncthreads();

    // ---- a2 = relu(bn2(c1+b)) into padded [colp=line*10+1+p][i2]@36, zero pads ----
    {
        float4 b1 = *(const float4*)(c1b + w * 16 + kg * 4);
        const int o2 = w * 8 + kg * 2;
        h2v sA = u2h(bn_pk[128 + o2]), sB = u2h(bn_pk[128 + o2 + 1]);
        h2v hA = u2h(bn_pk[160 + o2]), hB = u2h(bn_pk[160 + o2 + 1]);
#pragma unroll
        for (int nt = 0; nt < 4; nt++) {
            const int col = nt * 16 + l15;
            const int colp = (col >> 3) * 10 + 1 + (col & 7);
            h2v v0 = { (_Float16)(acc1[nt][0] + b1.x), (_Float16)(acc1[nt][1] + b1.y) };
            h2v v1 = { (_Float16)(acc1[nt][2] + b1.z), (_Float16)(acc1[nt][3] + b1.w) };
            v0 = relu2(v0 * sA + hA);
            v1 = relu2(v1 * sB + hB);
            uint2 u = { h2u(v0), h2u(v1) };
            *(uint2*)&abuf[colp * 36 + o2] = u;
        }
#pragma unroll
        for (int e = 0; e < 2; e++) {   // zero the 16 pad columns x 32 i2
            int idx = t * 2 + e;
            int pc = idx >> 5, i2 = idx & 31;
            int pl = pc >> 1, side = pc & 1;
            abuf[(pl * 10 + side * 9) * 36 + i2] = 0;
        }
    }
    __syncthreads();

    // ---- c2: 3-tap conv as 3 shifted GEMMs, K=64. wave w -> o-tile w ----
    f32x4 acc2[4];
#pragma unroll
    for (int nt = 0; nt < 4; nt++) acc2[nt] = (f32x4)0.f;
    {
        const int o = w * 16 + l15;
        const int colp0 = (l15 >> 3) * 10 + 1 + (l15 & 7);
#pragma unroll
        for (int tap = 0; tap < 3; tap++) {
            f16x8 wa0 = *(const f16x8*)(w2r + (tap * 64 + o) * 64 + ko8);
            f16x8 wa1 = *(const f16x8*)(w2r + (tap * 64 + o) * 64 + 32 + ko8);
#pragma unroll
            for (int nt = 0; nt < 4; nt++) {
                const int cp = colp0 + nt * 20 + tap - 1;
                f16x8 b0 = *(const f16x8*)&abuf[cp * 36 + kg * 4];
                f16x8 b1 = *(const f16x8*)&abuf[cp * 36 + 16 + kg * 4];
                acc2[nt] = __builtin_amdgcn_mfma_f32_16x16x32_f16(wa0, b0, acc2[nt], 0, 0, 0);
                acc2[nt] = __builtin_amdgcn_mfma_f32_16x16x32_f16(wa1, b1, acc2[nt], 0, 0, 0);
            }
        }
    }
    __syncthreads();

    // ---- a3 = relu(bn3(c2+b)) into [col][i2]@36 ----
    {
        float4 b2 = *(const float4*)(c2b + w * 16 + kg * 4);
        const int o2 = w * 8 + kg * 2;
        h2v sA = u2h(bn_pk[192 + o2]), sB = u2h(bn_pk[192 + o2 + 1]);
        h2v hA = u2h(bn_pk[224 + o2]), hB = u2h(bn_pk[224 + o2 + 1]);
#pragma unroll
        for (int nt = 0; nt < 4; nt++) {
            const int col = nt * 16 + l15;
            h2v v0 = { (_Float16)(acc2[nt][0] + b2.x), (_Float16)(acc2[nt][1] + b2.y) };
            h2v v1 = { (_Float16)(acc2[nt][2] + b2.z), (_Float16)(acc2[nt][3] + b2.w) };
            v0 = relu2(v0 * sA + hA);
            v1 = relu2(v1 * sB + hB);
            uint2 u = { h2u(v0), h2u(v1) };
            *(uint2*)&abuf[col * 36 + o2] = u;
        }
    }
    __syncthreads();

    // ---- c3: out[128o x 64col], K=64 + residual + relu -> y in-place into xp ----
    {
#pragma unroll
        for (int mi = 0; mi < 2; mi++) {
            const int om = (2 * w + mi) * 16 + l15;
            f16x8 af0 = *(const f16x8*)(w3r + om * 64 + ko8);
            f16x8 af1 = *(const f16x8*)(w3r + om * 64 + 32 + ko8);
            f32x4 acc3[4];
#pragma unroll
            for (int nt = 0; nt < 4; nt++) acc3[nt] = (f32x4)0.f;
#pragma unroll
            for (int nt = 0; nt < 4; nt++) {
                const int col = nt * 16 + l15;
                f16x8 b0 = *(const f16x8*)&abuf[col * 36 + kg * 4];
                f16x8 b1 = *(const f16x8*)&abuf[col * 36 + 16 + kg * 4];
                acc3[nt] = __builtin_amdgcn_mfma_f32_16x16x32_f16(af0, b0, acc3[nt], 0, 0, 0);
                acc3[nt] = __builtin_amdgcn_mfma_f32_16x16x32_f16(af1, b1, acc3[nt], 0, 0, 0);
            }
            float4 b3 = *(const float4*)(c3b + (2 * w + mi) * 16 + kg * 4);
            const int o2 = (2 * w + mi) * 8 + kg * 2;
#pragma unroll
            for (int nt = 0; nt < 4; nt++) {
                const int col = nt * 16 + l15;
                uint2 xv = *(const uint2*)&xp[col * 68 + o2];
                h2v y0 = { (_Float16)(acc3[nt][0] + b3.x), (_Float16)(acc3[nt][1] + b3.y) };
                h2v y1 = { (_Float16)(acc3[nt][2] + b3.z), (_Float16)(acc3[nt][3] + b3.w) };
                y0 = relu2(u2h(xv.x) + y0);
                y1 = relu2(u2h(xv.y) + y1);
                uint2 u = { h2u(y0), h2u(y1) };
                *(uint2*)&xp[col * 68 + o2] = u;
            }
        }
    }
    __syncthreads();

    // ---- fc2 partial (y from xp) + reduce ----
    {
        const int og = w;
        const int col = t & 63;
        const int obH = __builtin_amdgcn_readfirstlane(og * 16);  // o2 base
        const int p = col & 7, l = col >> 3;
        h2v yv[16];
#pragma unroll
        for (int j = 0; j < 16; j++) yv[j] = u2h(xp[col * 68 + obH + j]);
        float aj[4] = { 0.f, 0.f, 0.f, 0.f };
#pragma unroll
        for (int j = 0; j < 4; j++) {
            unsigned int wv2[16];
#pragma unroll
            for (int q = 0; q < 4; q++)
                *(uint4*)&wv2[q * 4] = *(const uint4*)(wfc2p + (j * 8 + p) * 64 + obH + q * 4);
#pragma unroll
            for (int j16 = 0; j16 < 16; j16++) aj[j] = fdot2(yv[j16], wv2[j16], aj[j]);
        }
#pragma unroll
        for (int off = 4; off > 0; off >>= 1) {
#pragma unroll
            for (int j = 0; j < 4; j++) aj[j] += __shfl_down(aj[j], off, 8);
        }
        if ((t & 7) == 0) {
#pragma unroll
            for (int j = 0; j < 4; j++) red[og * 32 + l * 4 + j] = aj[j];
        }
    }
    __syncthreads();

    // ---- final reduce + softmax ----
    if (t < 8) {
        float lg[4];
#pragma unroll
        for (int j = 0; j < 4; j++)
            lg[j] = bfc2[j] + red[t * 4 + j] + red[32 + t * 4 + j]
                  + red[64 + t * 4 + j] + red[96 + t * 4 + j];
        float mx = fmaxf(fmaxf(lg[0], lg[1]), fmaxf(lg[2], lg[3]));
        float e0 = expf(lg[0] - mx), e1 = expf(lg[1] - mx);
        float e2 = expf(lg[2] - mx), e3 = expf(lg[3] - mx);
        float s = 1.f / (e0 + e1 + e2 + e3);
        float4 r = { e0 * s, e1 * s, e2 * s, e3 * s };
        *(float4*)(out + (size_t)(n0 + t) * 4) = r;
    }
}

extern "C" void kernel_launch(void* const* d_in, const int* in_sizes, int n_in,
                              void* d_out, int out_size, void* d_ws, size_t ws_size,
                              hipStream_t stream) {
    const float* feature = (const float*)d_in[0];
    const float* lines   = (const float*)d_in[1];
    const float* w_fc1   = (const float*)d_in[2];
    const float* b_fc1   = (const float*)d_in[3];
    const float* bn1     = (const float*)d_in[4];
    const float* c1_w    = (const float*)d_in[5];
    const float* c1_b    = (const float*)d_in[6];
    const float* bn2     = (const float*)d_in[7];
    const float* c2_w    = (const float*)d_in[8];
    const float* c2_b    = (const float*)d_in[9];
    const float* bn3     = (const float*)d_in[10];
    const float* c3_w    = (const float*)d_in[11];
    const float* c3_b    = (const float*)d_in[12];
    const float* w_fc2   = (const float*)d_in[13];
    const float* b_fc2   = (const float*)d_in[14];
    float* out = (float*)d_out;

    char* ws = (char*)d_ws;
    unsigned int* X     = (unsigned int*)ws;                 // 33,554,432 B
    _Float16*     wf16  = (_Float16*)(ws + 33554432);        // 65,536 B
    _Float16*     w1r   = (_Float16*)(ws + 33619968);        // 16,384 B
    _Float16*     w2r   = (_Float16*)(ws + 33636352);        // 24,576 B
    _Float16*     w3r   = (_Float16*)(ws + 33660928);        // 16,384 B
    unsigned int* wfc2p = (unsigned int*)(ws + 33677312);    // 8,192 B
    unsigned int* bn_pk = (unsigned int*)(ws + 33685504);    // 1,024 B

    prep_small<<<249, 256, 0, stream>>>(w_fc1, c1_w, c2_w, c3_w, w_fc2, bn1, bn2, bn3,
                                        wf16, w1r, w2r, w3r, wfc2p, bn_pk);
    fc1_fused<<<1024, 512, 0, stream>>>(feature, wf16, b_fc1, X);
    line_v4<<<1250, 256, 0, stream>>>(X, lines, w1r, c1_b, w2r, c2_b,
                                      w3r, c3_b, wfc2p, b_fc2, bn_pk, out);
}

// Round 7
// 266.525 us; speedup vs baseline: 1.1042x; 1.0189x over previous
//
#include <hip/hip_runtime.h>
#include <math.h>
#include <stdint.h>

#define HH 256
#define LPB 5000

typedef _Float16 h2v  __attribute__((ext_vector_type(2)));
typedef _Float16 f16x8 __attribute__((ext_vector_type(8)));
typedef float    f32x4 __attribute__((ext_vector_type(4)));

__device__ __forceinline__ h2v u2h(unsigned int u) { return __builtin_bit_cast(h2v, u); }
__device__ __forceinline__ unsigned int h2u(h2v h) { return __builtin_bit_cast(unsigned int, h); }

__device__ __forceinline__ float fdot2(h2v a, unsigned int w, float c) {
#if __has_builtin(__builtin_amdgcn_fdot2)
    return __builtin_amdgcn_fdot2(a, u2h(w), c, false);
#else
    h2v b = u2h(w);
    return c + (float)a[0] * (float)b[0] + (float)a[1] * (float)b[1];
#endif
}

__device__ __forceinline__ h2v relu2(h2v a) {
    h2v z = (h2v)(_Float16)0.f;
#if __has_builtin(__builtin_elementwise_max)
    return __builtin_elementwise_max(a, z);
#else
    h2v r; r[0] = a[0] > z[0] ? a[0] : z[0]; r[1] = a[1] > z[1] ? a[1] : z[1]; return r;
#endif
}
__device__ __forceinline__ h2v hmax2v(h2v a, h2v b) {
#if __has_builtin(__builtin_elementwise_max)
    return __builtin_elementwise_max(a, b);
#else
    h2v r; r[0] = a[0] > b[0] ? a[0] : b[0]; r[1] = a[1] > b[1] ? a[1] : b[1]; return r;
#endif
}

// ---------------------------------------------------------------------------
// prep_small: f16 weight conversions (row-major for MFMA A-operands) + folded
// BN packs + fc2 weight pack.
// ---------------------------------------------------------------------------
__global__ __launch_bounds__(256) void prep_small(
    const float* __restrict__ w_fc1, const float* __restrict__ c1w,
    const float* __restrict__ c2w,  const float* __restrict__ c3w,
    const float* __restrict__ wfc2, const float* __restrict__ bn1,
    const float* __restrict__ bn2,  const float* __restrict__ bn3,
    _Float16* __restrict__ wf16, _Float16* __restrict__ w1r,
    _Float16* __restrict__ w2r, _Float16* __restrict__ w3r,
    unsigned int* __restrict__ wfc2p, unsigned int* __restrict__ bn_pk)
{
    int i = blockIdx.x * 256 + threadIdx.x;
    if (i < 32768) { wf16[i] = (_Float16)w_fc1[i]; return; }
    i -= 32768;
    if (i < 8192) {                       // w1r[o][c] (same layout as c1_w)
        w1r[i] = (_Float16)c1w[i]; return;
    }
    i -= 8192;
    if (i < 12288) {                      // w2r[tap][o][i] from c2_w[o][i][tap]
        int ii = i & 63, o = (i >> 6) & 63, tap = i >> 12;
        w2r[i] = (_Float16)c2w[(o * 64 + ii) * 3 + tap]; return;
    }
    i -= 12288;
    if (i < 8192) {                       // w3r[o][i] (same layout as c3_w)
        w3r[i] = (_Float16)c3w[i]; return;
    }
    i -= 8192;
    if (i < 2048) {                       // wfc2p[(j*8+p)*64 + c2]
        int c2 = i & 63, p = (i >> 6) & 7, j = i >> 9;
        h2v v = { (_Float16)wfc2[j * 1024 + (2 * c2) * 8 + p],
                  (_Float16)wfc2[j * 1024 + (2 * c2 + 1) * 8 + p] };
        wfc2p[(j * 8 + p) * 64 + c2] = h2u(v); return;
    }
    i -= 2048;
    if (i < 128) {                        // bn packs: scale, shift = beta - mean*scale
        const float* bn; int C, base, hcount;
        if (i < 64)      { bn = bn1; C = 128; base = 0;   hcount = 64; }
        else if (i < 96) { bn = bn2; C = 64;  base = 128; hcount = 32; i -= 64; }
        else             { bn = bn3; C = 64;  base = 192; hcount = 32; i -= 96; }
        int c0 = 2 * i, c1 = 2 * i + 1;
        float s0 = bn[c0] * rsqrtf(bn[3 * C + c0] + 1e-5f);
        float s1 = bn[c1] * rsqrtf(bn[3 * C + c1] + 1e-5f);
        float h0 = bn[C + c0] - bn[2 * C + c0] * s0;
        float h1 = bn[C + c1] - bn[2 * C + c1] * s1;
        h2v sv = { (_Float16)s0, (_Float16)s1 };
        h2v hv = { (_Float16)h0, (_Float16)h1 };
        bn_pk[base + i] = h2u(sv);
        bn_pk[base + hcount + i] = h2u(hv);
    }
}

// ---------------------------------------------------------------------------
// fc1_fused: round-1 verified version (best measured total, 268.2 us).
// f32 feature tile in LDS, f16 convert during fragment build, f16 MFMA.
// 128 pix x 128 o per block, K=256 in 8 steps, 256 threads, 4 blocks/CU.
// NOTE: dbuf (R3, -9us), transposed-f16 staging (R2, neutral), 512-thread
// TLP (R6, -3us) all measured worse/neutral -- do not reapply.
// ---------------------------------------------------------------------------
__global__ __launch_bounds__(256, 4) void fc1_fused(
    const float* __restrict__ feat,   // [B,256,65536]
    const _Float16* __restrict__ W,   // [128][256] f16
    const float* __restrict__ bias,
    unsigned int* __restrict__ X)     // [131072][64] h2 units
{
    __shared__ float Tf[32 * 132];    // f32 feature tile [c][pix], pad 132
    __shared__ _Float16 Wl[128 * 40]; // f16 W tile [o][k], pad 40
    const int t = threadIdx.x;
    const int lane = t & 63, wave = t >> 6;
    const int wm = wave & 1, wn = wave >> 1;
    const int pix0g = blockIdx.x << 7;              // global pixel base
    const int b = blockIdx.x >> 9;
    const int pix0l = pix0g & 65535;                // within batch
    const float* fbase = feat + (size_t)b * (256u * 65536u) + pix0l;

    f32x4 acc[4][4];
#pragma unroll
    for (int a = 0; a < 4; a++)
#pragma unroll
        for (int c = 0; c < 4; c++) acc[a][c] = (f32x4)0.f;

    for (int ks = 0; ks < 8; ks++) {
        const int k0 = ks * 32;
        __syncthreads();
#pragma unroll
        for (int r = 0; r < 4; r++) {               // 32 c x 128 pix f32
            int idx = t + r * 256;
            int c = idx >> 5, p4 = idx & 31;
            float4 v = *(const float4*)(fbase + (size_t)(k0 + c) * 65536 + p4 * 4);
            *(float4*)&Tf[c * 132 + p4 * 4] = v;
        }
#pragma unroll
        for (int r = 0; r < 2; r++) {               // 128 o x 32 k f16
            int idx = t + r * 256;
            int row = idx >> 2, ko = (idx & 3) * 8;
            *(uint4*)&Wl[row * 40 + ko] = *(const uint4*)(W + row * 256 + k0 + ko);
        }
        __syncthreads();
        f16x8 af[4], bf[4];
#pragma unroll
        for (int mt = 0; mt < 4; mt++)
            af[mt] = *(const f16x8*)&Wl[(wm * 64 + mt * 16 + (lane & 15)) * 40 + (lane >> 4) * 8];
#pragma unroll
        for (int nt = 0; nt < 4; nt++) {
            int q = wn * 64 + nt * 16 + (lane & 15);
            int cb = (lane >> 4) * 8;
            f16x8 v;
#pragma unroll
            for (int j = 0; j < 8; j++) v[j] = (_Float16)Tf[(cb + j) * 132 + q];
            bf[nt] = v;
        }
#pragma unroll
        for (int mt = 0; mt < 4; mt++)
#pragma unroll
            for (int nt = 0; nt < 4; nt++)
                acc[mt][nt] = __builtin_amdgcn_mfma_f32_16x16x32_f16(af[mt], bf[nt], acc[mt][nt], 0, 0, 0);
    }
#pragma unroll
    for (int mt = 0; mt < 4; mt++) {
        int o = wm * 64 + mt * 16 + (lane >> 4) * 4;
        float4 b4 = *(const float4*)(bias + o);
#pragma unroll
        for (int nt = 0; nt < 4; nt++) {
            int pix = pix0g + wn * 64 + nt * 16 + (lane & 15);
            f32x4 a = acc[mt][nt];
            h2v lo = { (_Float16)(a[0] + b4.x), (_Float16)(a[1] + b4.y) };
            h2v hi = { (_Float16)(a[2] + b4.z), (_Float16)(a[3] + b4.w) };
            uint2 v = { h2u(lo), h2u(hi) };
            *(uint2*)(X + (size_t)pix * 64 + (o >> 1)) = v;
        }
    }
}

// ---------------------------------------------------------------------------
// line_v4: round-1 verified version (best measured total), unchanged.
// NOTE: gather-hoist+setprio (R4, neutral), spatial sort+XCD swizzle
// (R5, -25us) measured worse/neutral -- do not reapply.
// ---------------------------------------------------------------------------
__global__ __launch_bounds__(256, 4) void line_v4(
    const unsigned int* __restrict__ X,      // [131072][64] h2 units
    const float* __restrict__ lines,
    const _Float16* __restrict__ w1r, const float* __restrict__ c1b,
    const _Float16* __restrict__ w2r, const float* __restrict__ c2b,
    const _Float16* __restrict__ w3r, const float* __restrict__ c3b,
    const unsigned int* __restrict__ wfc2p, const float* __restrict__ bfc2,
    const unsigned int* __restrict__ bn_pk,
    float* __restrict__ out)
{
    __shared__ int geoB[256];
    __shared__ unsigned int geoWA[256], geoWB[256];
    __shared__ unsigned int xp[64 * 68];     // raw pooled feats [col][o2], 17408 B
    __shared__ unsigned int abuf[64 * 68];   // a1 [col][c2]@68 -> a2 [colp80][i2]@36 -> a3 [col][i2]@36
    __shared__ float red[128];

    const int t = threadIdx.x;
    const int n0 = blockIdx.x * 8;
    const int lane = t & 63;
    const int w = t >> 6;
    const int l15 = lane & 15;
    const int kg = lane >> 4;            // k-group 0..3
    const int ko8 = kg * 8;              // k offset in halves

    // ---- geometry: one thread per sample point ----
    {
        int l = t >> 5, k = t & 31;
        int n = n0 + l;
        float4 ln = *(const float4*)(lines + n * 4);
        float lam = (float)k / 31.0f;
        float px = ln.x * lam + ln.z * (1.f - lam) - 0.5f;
        float py = ln.y * lam + ln.w * (1.f - lam) - 0.5f;
        float px0 = fminf(fmaxf(floorf(px), 0.f), 255.f);
        float py0 = fminf(fmaxf(floorf(py), 0.f), 255.f);
        float dx = px - px0, dy = py - py0;
        float ex = 1.f - dx, ey = 1.f - dy;
        h2v wA = { (_Float16)(ex * ey), (_Float16)(dx * ey) };
        h2v wB = { (_Float16)(ex * dy), (_Float16)(dx * dy) };
        int b = (n >= LPB) ? 1 : 0;
        int pixflat = (b << 16) + ((int)px0 << 8) + (int)py0;
        geoB[t] = pixflat << 6;                  // h2-unit index
        geoWA[t] = h2u(wA); geoWB[t] = h2u(wB);
    }
    __syncthreads();

    // ---- gather + maxpool4, dual write: raw -> xp, relu(bn1(.)) -> abuf ----
    {
        const int c8 = t & 15;          // channel-oct 0..15 (8 ch each)
        const int sub = t >> 4;         // 0..15
        const int line = sub >> 1;
        const int gbase = (sub & 1) * 4;
        const uint4* xq = (const uint4*)X;
        uint4 s1 = *(const uint4*)(bn_pk + c8 * 4);
        uint4 h1 = *(const uint4*)(bn_pk + 64 + c8 * 4);
#pragma unroll
        for (int lg = 0; lg < 4; lg++) {
            int g = gbase + lg;
            int ptb = line * 32 + g * 4;
            h2v m0, m1, m2, m3;
#pragma unroll
            for (int s = 0; s < 4; s++) {
                int pt = ptb + s;
                int base4 = (geoB[pt] >> 2) + c8;
                h2v wA = u2h(geoWA[pt]), wB = u2h(geoWB[pt]);
                uint4 q00 = xq[base4];
                uint4 q10 = xq[base4 + 4096];
                uint4 q01 = xq[base4 + 16];
                uint4 q11 = xq[base4 + 4112];
                h2v w00 = { wA[0], wA[0] }, w10 = { wA[1], wA[1] };
                h2v w01 = { wB[0], wB[0] }, w11 = { wB[1], wB[1] };
                h2v v0 = u2h(q00.x) * w00 + u2h(q10.x) * w10 + u2h(q01.x) * w01 + u2h(q11.x) * w11;
                h2v v1 = u2h(q00.y) * w00 + u2h(q10.y) * w10 + u2h(q01.y) * w01 + u2h(q11.y) * w11;
                h2v v2 = u2h(q00.z) * w00 + u2h(q10.z) * w10 + u2h(q01.z) * w01 + u2h(q11.z) * w11;
                h2v v3 = u2h(q00.w) * w00 + u2h(q10.w) * w10 + u2h(q01.w) * w01 + u2h(q11.w) * w11;
                if (s == 0) { m0 = v0; m1 = v1; m2 = v2; m3 = v3; }
                else { m0 = hmax2v(m0, v0); m1 = hmax2v(m1, v1);
                       m2 = hmax2v(m2, v2); m3 = hmax2v(m3, v3); }
            }
            int colw = line * 8 + g;
            uint4 raw = { h2u(m0), h2u(m1), h2u(m2), h2u(m3) };
            *(uint4*)&xp[colw * 68 + c8 * 4] = raw;
            h2v r0 = relu2(m0 * u2h(s1.x) + u2h(h1.x));
            h2v r1 = relu2(m1 * u2h(s1.y) + u2h(h1.y));
            h2v r2 = relu2(m2 * u2h(s1.z) + u2h(h1.z));
            h2v r3 = relu2(m3 * u2h(s1.w) + u2h(h1.w));
            uint4 act = { h2u(r0), h2u(r1), h2u(r2), h2u(r3) };
            *(uint4*)&abuf[colw * 68 + c8 * 4] = act;
        }
    }
    __syncthreads();

    // ---- c1: out[64o x 64col], K=128 MFMA. wave w -> o-tile w ----
    f32x4 acc1[4];
#pragma unroll
    for (int nt = 0; nt < 4; nt++) acc1[nt] = (f32x4)0.f;
    {
        const int o = w * 16 + l15;
        f16x8 af[4];
#pragma unroll
        for (int kt = 0; kt < 4; kt++)
            af[kt] = *(const f16x8*)(w1r + o * 128 + kt * 32 + ko8);
#pragma unroll
        for (int nt = 0; nt < 4; nt++) {
            const int colb = nt * 16 + l15;
#pragma unroll
            for (int kt = 0; kt < 4; kt++) {
                f16x8 bf = *(const f16x8*)&abuf[colb * 68 + kt * 16 + kg * 4];
                acc1[nt] = __builtin_amdgcn_mfma_f32_16x16x32_f16(af[kt], bf, acc1[nt], 0, 0, 0);
            }
        }
    }
    __syncthreads();

    // ---- a2 = relu(bn2(c1+b)) into padded [colp=line*10+1+p][i2]@36, zero pads ----
    {
        float4 b1 = *(const float4*)(c1b + w * 16 + kg * 4);
        const int o2 = w * 8 + kg * 2;
        h2v sA = u2h(bn_pk[128 + o2]), sB = u2h(bn_pk[128 + o2 + 1]);
        h2v hA = u2h(bn_pk[160 + o2]), hB = u2h(bn_pk[160 + o2 + 1]);
#pragma unroll
        for (int nt = 0; nt < 4; nt++) {
            const int col = nt * 16 + l15;
            const int colp = (col >> 3) * 10 + 1 + (col & 7);
            h2v v0 = { (_Float16)(acc1[nt][0] + b1.x), (_Float16)(acc1[nt][1] + b1.y) };
            h2v v1 = { (_Float16)(acc1[nt][2] + b1.z), (_Float16)(acc1[nt][3] + b1.w) };
            v0 = relu2(v0 * sA + hA);
            v1 = relu2(v1 * sB + hB);
            uint2 u = { h2u(v0), h2u(v1) };
            *(uint2*)&abuf[colp * 36 + o2] = u;
        }
#pragma unroll
        for (int e = 0; e < 2; e++) {   // zero the 16 pad columns x 32 i2
            int idx = t * 2 + e;
            int pc = idx >> 5, i2 = idx & 31;
            int pl = pc >> 1, side = pc & 1;
            abuf[(pl * 10 + side * 9) * 36 + i2] = 0;
        }
    }
    __syncthreads();

    // ---- c2: 3-tap conv as 3 shifted GEMMs, K=64. wave w -> o-tile w ----
    f32x4 acc2[4];
#pragma unroll
    for (int nt = 0; nt < 4; nt++) acc2[nt] = (f32x4)0.f;
    {
        const int o = w * 16 + l15;
        const int colp0 = (l15 >> 3) * 10 + 1 + (l15 & 7);
#pragma unroll
        for (int tap = 0; tap < 3; tap++) {
            f16x8 wa0 = *(const f16x8*)(w2r + (tap * 64 + o) * 64 + ko8);
            f16x8 wa1 = *(const f16x8*)(w2r + (tap * 64 + o) * 64 + 32 + ko8);
#pragma unroll
            for (int nt = 0; nt < 4; nt++) {
                const int cp = colp0 + nt * 20 + tap - 1;
                f16x8 b0 = *(const f16x8*)&abuf[cp * 36 + kg * 4];
                f16x8 b1 = *(const f16x8*)&abuf[cp * 36 + 16 + kg * 4];
                acc2[nt] = __builtin_amdgcn_mfma_f32_16x16x32_f16(wa0, b0, acc2[nt], 0, 0, 0);
                acc2[nt] = __builtin_amdgcn_mfma_f32_16x16x32_f16(wa1, b1, acc2[nt], 0, 0, 0);
            }
        }
    }
    __syncthreads();

    // ---- a3 = relu(bn3(c2+b)) into [col][i2]@36 ----
    {
        float4 b2 = *(const float4*)(c2b + w * 16 + kg * 4);
        const int o2 = w * 8 + kg * 2;
        h2v sA = u2h(bn_pk[192 + o2]), sB = u2h(bn_pk[192 + o2 + 1]);
        h2v hA = u2h(bn_pk[224 + o2]), hB = u2h(bn_pk[224 + o2 + 1]);
#pragma unroll
        for (int nt = 0; nt < 4; nt++) {
            const int col = nt * 16 + l15;
            h2v v0 = { (_Float16)(acc2[nt][0] + b2.x), (_Float16)(acc2[nt][1] + b2.y) };
            h2v v1 = { (_Float16)(acc2[nt][2] + b2.z), (_Float16)(acc2[nt][3] + b2.w) };
            v0 = relu2(v0 * sA + hA);
            v1 = relu2(v1 * sB + hB);
            uint2 u = { h2u(v0), h2u(v1) };
            *(uint2*)&abuf[col * 36 + o2] = u;
        }
    }
    __syncthreads();

    // ---- c3: out[128o x 64col], K=64 + residual + relu -> y in-place into xp ----
    {
#pragma unroll
        for (int mi = 0; mi < 2; mi++) {
            const int om = (2 * w + mi) * 16 + l15;
            f16x8 af0 = *(const f16x8*)(w3r + om * 64 + ko8);
            f16x8 af1 = *(const f16x8*)(w3r + om * 64 + 32 + ko8);
            f32x4 acc3[4];
#pragma unroll
            for (int nt = 0; nt < 4; nt++) acc3[nt] = (f32x4)0.f;
#pragma unroll
            for (int nt = 0; nt < 4; nt++) {
                const int col = nt * 16 + l15;
                f16x8 b0 = *(const f16x8*)&abuf[col * 36 + kg * 4];
                f16x8 b1 = *(const f16x8*)&abuf[col * 36 + 16 + kg * 4];
                acc3[nt] = __builtin_amdgcn_mfma_f32_16x16x32_f16(af0, b0, acc3[nt], 0, 0, 0);
                acc3[nt] = __builtin_amdgcn_mfma_f32_16x16x32_f16(af1, b1, acc3[nt], 0, 0, 0);
            }
            float4 b3 = *(const float4*)(c3b + (2 * w + mi) * 16 + kg * 4);
            const int o2 = (2 * w + mi) * 8 + kg * 2;
#pragma unroll
            for (int nt = 0; nt < 4; nt++) {
                const int col = nt * 16 + l15;
                uint2 xv = *(const uint2*)&xp[col * 68 + o2];
                h2v y0 = { (_Float16)(acc3[nt][0] + b3.x), (_Float16)(acc3[nt][1] + b3.y) };
                h2v y1 = { (_Float16)(acc3[nt][2] + b3.z), (_Float16)(acc3[nt][3] + b3.w) };
                y0 = relu2(u2h(xv.x) + y0);
                y1 = relu2(u2h(xv.y) + y1);
                uint2 u = { h2u(y0), h2u(y1) };
                *(uint2*)&xp[col * 68 + o2] = u;
            }
        }
    }
    __syncthreads();

    // ---- fc2 partial (y from xp) + reduce ----
    {
        const int og = w;
        const int col = t & 63;
        const int obH = __builtin_amdgcn_readfirstlane(og * 16);  // o2 base
        const int p = col & 7, l = col >> 3;
        h2v yv[16];
#pragma unroll
        for (int j = 0; j < 16; j++) yv[j] = u2h(xp[col * 68 + obH + j]);
        float aj[4] = { 0.f, 0.f, 0.f, 0.f };
#pragma unroll
        for (int j = 0; j < 4; j++) {
            unsigned int wv2[16];
#pragma unroll
            for (int q = 0; q < 4; q++)
                *(uint4*)&wv2[q * 4] = *(const uint4*)(wfc2p + (j * 8 + p) * 64 + obH + q * 4);
#pragma unroll
            for (int j16 = 0; j16 < 16; j16++) aj[j] = fdot2(yv[j16], wv2[j16], aj[j]);
        }
#pragma unroll
        for (int off = 4; off > 0; off >>= 1) {
#pragma unroll
            for (int j = 0; j < 4; j++) aj[j] += __shfl_down(aj[j], off, 8);
        }
        if ((t & 7) == 0) {
#pragma unroll
            for (int j = 0; j < 4; j++) red[og * 32 + l * 4 + j] = aj[j];
        }
    }
    __syncthreads();

    // ---- final reduce + softmax ----
    if (t < 8) {
        float lg[4];
#pragma unroll
        for (int j = 0; j < 4; j++)
            lg[j] = bfc2[j] + red[t * 4 + j] + red[32 + t * 4 + j]
                  + red[64 + t * 4 + j] + red[96 + t * 4 + j];
        float mx = fmaxf(fmaxf(lg[0], lg[1]), fmaxf(lg[2], lg[3]));
        float e0 = expf(lg[0] - mx), e1 = expf(lg[1] - mx);
        float e2 = expf(lg[2] - mx), e3 = expf(lg[3] - mx);
        float s = 1.f / (e0 + e1 + e2 + e3);
        float4 r = { e0 * s, e1 * s, e2 * s, e3 * s };
        *(float4*)(out + (size_t)(n0 + t) * 4) = r;
    }
}

extern "C" void kernel_launch(void* const* d_in, const int* in_sizes, int n_in,
                              void* d_out, int out_size, void* d_ws, size_t ws_size,
                              hipStream_t stream) {
    const float* feature = (const float*)d_in[0];
    const float* lines   = (const float*)d_in[1];
    const float* w_fc1   = (const float*)d_in[2];
    const float* b_fc1   = (const float*)d_in[3];
    const float* bn1     = (const float*)d_in[4];
    const float* c1_w    = (const float*)d_in[5];
    const float* c1_b    = (const float*)d_in[6];
    const float* bn2     = (const float*)d_in[7];
    const float* c2_w    = (const float*)d_in[8];
    const float* c2_b    = (const float*)d_in[9];
    const float* bn3     = (const float*)d_in[10];
    const float* c3_w    = (const float*)d_in[11];
    const float* c3_b    = (const float*)d_in[12];
    const float* w_fc2   = (const float*)d_in[13];
    const float* b_fc2   = (const float*)d_in[14];
    float* out = (float*)d_out;

    char* ws = (char*)d_ws;
    unsigned int* X     = (unsigned int*)ws;                 // 33,554,432 B
    _Float16*     wf16  = (_Float16*)(ws + 33554432);        // 65,536 B
    _Float16*     w1r   = (_Float16*)(ws + 33619968);        // 16,384 B
    _Float16*     w2r   = (_Float16*)(ws + 33636352);        // 24,576 B
    _Float16*     w3r   = (_Float16*)(ws + 33660928);        // 16,384 B
    unsigned int* wfc2p = (unsigned int*)(ws + 33677312);    // 8,192 B
    unsigned int* bn_pk = (unsigned int*)(ws + 33685504);    // 1,024 B

    prep_small<<<249, 256, 0, stream>>>(w_fc1, c1_w, c2_w, c3_w, w_fc2, bn1, bn2, bn3,
                                        wf16, w1r, w2r, w3r, wfc2p, bn_pk);
    fc1_fused<<<1024, 256, 0, stream>>>(feature, wf16, b_fc1, X);
    line_v4<<<1250, 256, 0, stream>>>(X, lines, w1r, c1_b, w2r, c2_b,
                                      w3r, c3_b, wfc2p, b_fc2, bn_pk, out);
}